// Round 5
// baseline (283.045 us; speedup 1.0000x reference)
//
#include <hip/hip_runtime.h>
#include <stdint.h>

#define TT_ 2048
#define CC_ 1024

typedef unsigned short u16;
typedef __bf16 bf16x8 __attribute__((ext_vector_type(8)));
typedef float f32x4 __attribute__((ext_vector_type(4)));
typedef unsigned short u16x8 __attribute__((ext_vector_type(8)));
typedef unsigned int u32x2 __attribute__((ext_vector_type(2)));

__device__ __forceinline__ u16 f2bf(float f) {
  unsigned u = __float_as_uint(f);
  u += 0x7fff + ((u >> 16) & 1);
  return (u16)(u >> 16);
}
__device__ __forceinline__ float bf2f(u16 v) {
  return __uint_as_float(((unsigned)v) << 16);
}

__device__ __forceinline__ float gelu_f(float t) {
  float u = 1.5957691216057308f * (t + 0.044715f * t * t * t);
  return t / (1.f + __expf(-u));
}

__device__ __forceinline__ void async_cp16(const u16* g, u16* l) {
  __builtin_amdgcn_global_load_lds(
      (const __attribute__((address_space(1))) void*)(uintptr_t)g,
      (__attribute__((address_space(3))) void*)(uint32_t)(uintptr_t)l,
      16, 0, 0);
}

__device__ __forceinline__ void blockbar() {
  asm volatile("" ::: "memory");
  __builtin_amdgcn_s_barrier();
  asm volatile("" ::: "memory");
}

// ---- transpose + convert: W[K][N] f32 -> WT[N][K] bf16 ----
__global__ __launch_bounds__(256) void kconv_t(const float* __restrict__ W,
                                               u16* __restrict__ WT, int K, int N) {
  __shared__ float t[32][33];
  int n0 = blockIdx.x * 32, k0 = blockIdx.y * 32;
  int tx = threadIdx.x & 31, ty = threadIdx.x >> 5;
#pragma unroll
  for (int r = 0; r < 4; ++r)
    t[ty + 8 * r][tx] = W[(size_t)(k0 + ty + 8 * r) * N + n0 + tx];
  __syncthreads();
#pragma unroll
  for (int r = 0; r < 4; ++r)
    WT[(size_t)(n0 + ty + 8 * r) * K + k0 + tx] = f2bf(t[tx][ty + 8 * r]);
}

// ---- layernorm rows of 1024: f32 in -> bf16 out ----
__global__ __launch_bounds__(256) void kln(const float* __restrict__ x,
                                           const float* __restrict__ g,
                                           const float* __restrict__ b,
                                           u16* __restrict__ out) {
  int row = blockIdx.x, tid = threadIdx.x;
  const float4* xr = (const float4*)(x + (size_t)row * CC_);
  float4 v = xr[tid];
  float s = v.x + v.y + v.z + v.w;
  float s2 = v.x * v.x + v.y * v.y + v.z * v.z + v.w * v.w;
#pragma unroll
  for (int off = 32; off; off >>= 1) { s += __shfl_down(s, off); s2 += __shfl_down(s2, off); }
  __shared__ float rs[4], rq[4];
  int w = tid >> 6;
  if ((tid & 63) == 0) { rs[w] = s; rq[w] = s2; }
  __syncthreads();
  s = rs[0] + rs[1] + rs[2] + rs[3];
  s2 = rq[0] + rq[1] + rq[2] + rq[3];
  float mean = s * (1.f / CC_);
  float var = s2 * (1.f / CC_) - mean * mean;
  float rstd = rsqrtf(var + 1e-5f);
  float4 gv = ((const float4*)g)[tid];
  float4 bv = ((const float4*)b)[tid];
  u16* orow = out + (size_t)row * CC_ + tid * 4;
  orow[0] = f2bf((v.x - mean) * rstd * gv.x + bv.x);
  orow[1] = f2bf((v.y - mean) * rstd * gv.y + bv.y);
  orow[2] = f2bf((v.z - mean) * rstd * gv.z + bv.z);
  orow[3] = f2bf((v.w - mean) * rstd * gv.w + bv.w);
}

// ---- old 128x128 GEMM (kept for ap) ----
template <int EPI, int NSPLIT>
__global__ __launch_bounds__(256) void kgemm(const u16* __restrict__ A,
                                             const u16* __restrict__ BTm,
                                             const float* __restrict__ bias,
                                             const float* __restrict__ resid,
                                             void* __restrict__ out,
                                             float* __restrict__ part,
                                             int M, int N, int Ktot) {
  __shared__ __align__(16) u16 As[2][128 * 32];
  __shared__ __align__(16) u16 Bs[2][128 * 32];
  const int tid = threadIdx.x, lane = tid & 63, w = tid >> 6;
  const int llo = lane & 15, lhi = lane >> 4;
  const int row0 = blockIdx.y * 128, col0 = blockIdx.x * 128;
  const int wr = w >> 1, wc = w & 1;
  const int crow = lane >> 2;
  const int ck = (lane & 3) * 8;
  const int Kc = Ktot / NSPLIT;
  const int klo = (NSPLIT > 1) ? blockIdx.z * Kc : 0;

  f32x4 acc[4][4] = {};

  auto stage = [&](int bufi, int kof) {
#pragma unroll
    for (int c = w; c < 8; c += 4) {
      int r = c * 16 + crow;
      async_cp16(A + (size_t)(row0 + r) * Ktot + klo + kof + ck, &As[bufi][c * 512]);
      async_cp16(BTm + (size_t)(col0 + r) * Ktot + klo + kof + ck, &Bs[bufi][c * 512]);
    }
  };

  const int nt = Kc / 32;
  stage(0, 0);
  asm volatile("s_waitcnt vmcnt(0)" ::: "memory");
  blockbar();
  int cur = 0;

  for (int t = 0; t < nt; ++t) {
    if (t + 1 < nt) stage(cur ^ 1, (t + 1) * 32);
    bf16x8 af[4], bfr[4];
#pragma unroll
    for (int m = 0; m < 4; ++m)
      af[m] = *(const bf16x8*)&As[cur][(wr * 64 + m * 16 + llo) * 32 + lhi * 8];
#pragma unroll
    for (int n = 0; n < 4; ++n)
      bfr[n] = *(const bf16x8*)&Bs[cur][(wc * 64 + n * 16 + llo) * 32 + lhi * 8];
#pragma unroll
    for (int m = 0; m < 4; ++m)
#pragma unroll
      for (int n = 0; n < 4; ++n)
        acc[m][n] = __builtin_amdgcn_mfma_f32_16x16x32_bf16(af[m], bfr[n], acc[m][n], 0, 0, 0);
    if (t + 1 < nt) {
      asm volatile("s_waitcnt vmcnt(0)" ::: "memory");
      blockbar();
    }
    cur ^= 1;
  }

  const int c_row = row0 + wr * 64 + lhi * 4;
  const int c_col = col0 + wc * 64 + llo;
  const bool fin = (NSPLIT == 1) || (blockIdx.z == 0);
#pragma unroll
  for (int n = 0; n < 4; ++n) {
    int col = c_col + n * 16;
    float bb = bias[col];
#pragma unroll
    for (int m = 0; m < 4; ++m) {
      f32x4 a = acc[m][n];
#pragma unroll
      for (int i = 0; i < 4; ++i) {
        size_t idx = (size_t)(c_row + m * 16 + i) * N + col;
        if (!fin) {
          part[idx] = a[i];
        } else {
          float val = a[i] + bb;
          if constexpr (EPI == 1) {
            ((float*)out)[idx] = val + resid[idx];
          } else if constexpr (EPI == 2) {
            ((u16*)out)[idx] = f2bf(gelu_f(val));
          } else {
            ((u16*)out)[idx] = f2bf(val);
          }
        }
      }
    }
  }
}

// ---- 256x256 GEMM, BK=32, 4-slot LDS ring, distance-3 prefetch, counted vmcnt ----
// 8 waves (2M x 4N), per-wave 128x64 output. EPI as kgemm. NSPLIT>1: z=0 epilogue,
// z>0 writes bf16 raw partial at part + (z-1)*M*N.
template <int EPI, int NSPLIT>
__global__ __launch_bounds__(512, 2) void kgemm2(const u16* __restrict__ A,
                                                 const u16* __restrict__ BTm,
                                                 const float* __restrict__ bias,
                                                 const float* __restrict__ resid,
                                                 void* __restrict__ out,
                                                 u16* __restrict__ part,
                                                 int M, int N, int Ktot) {
  __shared__ __align__(16) u16 LB[4][2][8192];  // [slot][A/B][256 rows x 32 k]
  const int tid = threadIdx.x, lane = tid & 63, w = tid >> 6;
  const int llo = lane & 15, lhi = lane >> 4;
  const int wr = w >> 2, wc = w & 3;
  const int row0 = blockIdx.y * 256, col0 = blockIdx.x * 256;
  const int Kc = Ktot / NSPLIT;
  const int klo = (NSPLIT > 1) ? blockIdx.z * Kc : 0;
  const int nt = Kc / 32;

  // staging: 4 waves share A-half wr (sub-id wsA), 4 waves share B-half hbB (sub-id wsB)
  const int wsA = w & 3;
  const int hbB = (wc >> 1);
  const int wsB = (w & 1) + ((w >> 2) << 1);

  const u16 *gA[2], *gB[2];
  int ldsA[2], ldsB[2];
#pragma unroll
  for (int l = 0; l < 2; ++l) {
    int c = l * 256 + wsA * 64 + lane;             // 16B-chunk id within half (0..511)
    int rowl = c >> 2;
    int kc = ((c & 3) ^ ((c >> 3) & 3)) * 8;       // swizzled source k-chunk
    gA[l] = A + (size_t)(row0 + wr * 128 + rowl) * Ktot + klo + kc;
    ldsA[l] = wr * 4096 + (l * 256 + wsA * 64) * 8;  // wave-uniform (u16 units)
    int c2 = l * 256 + wsB * 64 + lane;
    int row2 = c2 >> 2;
    int kc2 = ((c2 & 3) ^ ((c2 >> 3) & 3)) * 8;
    gB[l] = BTm + (size_t)(col0 + hbB * 128 + row2) * Ktot + klo + kc2;
    ldsB[l] = hbB * 4096 + (l * 256 + wsB * 64) * 8;
  }

  auto stage = [&](int t) {
    int slot = t & 3;
#pragma unroll
    for (int l = 0; l < 2; ++l) {
      async_cp16(gA[l] + (size_t)t * 32, &LB[slot][0][ldsA[l]]);
      async_cp16(gB[l] + (size_t)t * 32, &LB[slot][1][ldsB[l]]);
    }
  };

  f32x4 acc[8][4] = {};
  for (int t = 0; t < 3 && t < nt; ++t) stage(t);
  const int swz = (llo >> 1) & 3;
  const int aoffb = wr * 4096 + llo * 32 + (lhi ^ swz) * 8;
  const int boffb = hbB * 4096 + ((wc & 1) * 64 + llo) * 32 + (lhi ^ swz) * 8;

  for (int t = 0; t < nt; ++t) {
    const int slot = t & 3;
    const int rem = nt - 1 - t;
    if (rem >= 2)      asm volatile("s_waitcnt vmcnt(8)" ::: "memory");
    else if (rem == 1) asm volatile("s_waitcnt vmcnt(4)" ::: "memory");
    else               asm volatile("s_waitcnt vmcnt(0)" ::: "memory");
    asm volatile("s_waitcnt lgkmcnt(0)" ::: "memory");  // prev iter's ds_reads drained
    blockbar();
    if (t + 3 < nt) stage(t + 3);

    bf16x8 af[8], bfv[4];
#pragma unroll
    for (int n = 0; n < 4; ++n)
      bfv[n] = *(const bf16x8*)&LB[slot][1][boffb + n * 512];
#pragma unroll
    for (int m = 0; m < 8; ++m)
      af[m] = *(const bf16x8*)&LB[slot][0][aoffb + m * 512];
    __builtin_amdgcn_s_setprio(1);
#pragma unroll
    for (int m = 0; m < 8; ++m)
#pragma unroll
      for (int n = 0; n < 4; ++n)
        acc[m][n] = __builtin_amdgcn_mfma_f32_16x16x32_bf16(af[m], bfv[n], acc[m][n], 0, 0, 0);
    __builtin_amdgcn_s_setprio(0);
  }

  const int c_row0 = row0 + wr * 128 + lhi * 4;
  const int c_col0 = col0 + wc * 64 + llo;
  const bool fin = (NSPLIT == 1) || (blockIdx.z == 0);
  u16* pb = part + (NSPLIT > 1 ? ((size_t)(blockIdx.z - 1)) * M * N : 0);
#pragma unroll
  for (int n = 0; n < 4; ++n) {
    int col = c_col0 + n * 16;
    float bb = bias[col];
#pragma unroll
    for (int m = 0; m < 8; ++m) {
      f32x4 a = acc[m][n];
#pragma unroll
      for (int i = 0; i < 4; ++i) {
        size_t idx = (size_t)(c_row0 + m * 16 + i) * N + col;
        if (!fin) {
          pb[idx] = f2bf(a[i]);
        } else {
          float val = a[i] + bb;
          if constexpr (EPI == 1) {
            ((float*)out)[idx] = val + resid[idx];
          } else if constexpr (EPI == 2) {
            ((u16*)out)[idx] = f2bf(gelu_f(val));
          } else {
            ((u16*)out)[idx] = f2bf(val);
          }
        }
      }
    }
  }
}

// ---- out[i] += p1[i]+p2[i]+p3[i] (bf16 partials) ----
__global__ __launch_bounds__(256) void kadd3(float* __restrict__ out,
                                             const u16* __restrict__ p, size_t MN) {
  size_t i0 = ((size_t)blockIdx.x * 256 + threadIdx.x) * 8;
  float4 o0 = *(float4*)(out + i0);
  float4 o1 = *(float4*)(out + i0 + 4);
#pragma unroll
  for (int s = 0; s < 3; ++s) {
    u16x8 v = *(const u16x8*)(p + s * MN + i0);
    o0.x += bf2f(v[0]); o0.y += bf2f(v[1]); o0.z += bf2f(v[2]); o0.w += bf2f(v[3]);
    o1.x += bf2f(v[4]); o1.y += bf2f(v[5]); o1.z += bf2f(v[6]); o1.w += bf2f(v[7]);
  }
  *(float4*)(out + i0) = o0;
  *(float4*)(out + i0 + 4) = o1;
}

// ---- V transpose: qkv[.][2048+h*64+d] -> VT[bh][d][T] bf16 ----
__global__ __launch_bounds__(256) void kvtrans(const u16* __restrict__ qkv,
                                               u16* __restrict__ VT) {
  int tt = blockIdx.x;
  int bh = blockIdx.y;
  int b = bh >> 4, h = bh & 15;
  __shared__ u16 t[64][72];
  int r = threadIdx.x >> 3, c0 = (threadIdx.x & 7) * 8;
  const u16* src = qkv + (size_t)(b * TT_ + tt * 64) * 3072 + 2048 + h * 64;
#pragma unroll
  for (int it = 0; it < 2; ++it) {
    int rr = r + it * 32;
    *(u16x8*)&t[rr][c0] = *(const u16x8*)(src + (size_t)rr * 3072 + c0);
  }
  __syncthreads();
  u16* dst = VT + ((size_t)bh * 64) * TT_ + tt * 64;
#pragma unroll
  for (int it = 0; it < 2; ++it) {
    int d = r + it * 32;
    u16x8 v;
#pragma unroll
    for (int e = 0; e < 8; ++e) v[e] = t[c0 + e][d];
    *(u16x8*)(dst + (size_t)d * TT_ + c0) = v;
  }
}

// ---- causal flash attention (unchanged from round 4) ----
__global__ __launch_bounds__(512, 4) void kattn(const u16* __restrict__ qkv,
                                                const u16* __restrict__ VT,
                                                u16* __restrict__ y) {
  const int h = blockIdx.x, b = blockIdx.y;
  const int z = blockIdx.z;
  const int qt = (z < 8) ? (15 - z) : (z - 8);
  const int tid = threadIdx.x, lane = tid & 63, w = tid >> 6;
  const int llo = lane & 15, lhi = lane >> 4;

  __shared__ __align__(16) u16 Qs[128 * 64];
  __shared__ __align__(16) u16 Ks[2][64 * 64];
  __shared__ __align__(16) u16 Vs[2][64 * 64];
  __shared__ __align__(16) u16 Ps[128 * 72];

  const size_t tok0 = (size_t)b * TT_;
  const int q0 = qt * 128;
  const u16* qb = qkv + tok0 * 3072 + h * 64;
  const u16* kb = qb + 1024;

  {
    const float alpha = 0.18033688011112042f;
    int r8 = tid >> 3, ce = (tid & 7) * 8;
#pragma unroll
    for (int it = 0; it < 2; ++it) {
      int tk = it * 64 + r8;
      u16x8 v = *(const u16x8*)(qb + (size_t)(q0 + tk) * 3072 + ce);
#pragma unroll
      for (int e = 0; e < 8; ++e) v[e] = f2bf(bf2f(v[e]) * alpha);
      *(u16x8*)&Qs[tk * 64 + (ce ^ ((tk & 7) << 3))] = v;
    }
  }
  asm volatile("s_waitcnt lgkmcnt(0)" ::: "memory");

  const int p_ = w * 8 + (lane >> 3);
  const int krow = ((p_ & 15) << 2) | (p_ >> 4);
  const int scol = ((lane & 7) * 8) ^ ((p_ & 7) << 3);
  const u16* kg = kb + (size_t)krow * 3072 + scol;
  const u16* vg = VT + ((size_t)(b * 16 + h) * 64 + p_) * TT_ + scol;

  const int ntiles = 2 * qt + 2;
  async_cp16(kg, &Ks[0][w * 512]);
  async_cp16(vg, &Vs[0][w * 512]);

  blockbar();

  bf16x8 aq[2];
#pragma unroll
  for (int kk = 0; kk < 2; ++kk)
    aq[kk] = *(const bf16x8*)&Qs[(w * 16 + llo) * 64 + ((kk * 32 + lhi * 8) ^ ((llo & 7) << 3))];

  float m_i[4], l_i[4];
  f32x4 o[4] = {};
#pragma unroll
  for (int i = 0; i < 4; ++i) { m_i[i] = -1e30f; l_i[i] = 0.f; }

  const int row_min = q0 + w * 16, row_max = row_min + 15;
  int buf = 0;

  for (int j = 0; j < ntiles; ++j) {
    if (j + 1 < ntiles) {
      async_cp16(kg + (size_t)(j + 1) * (64 * 3072), &Ks[buf ^ 1][w * 512]);
      async_cp16(vg + (size_t)(j + 1) * 64, &Vs[buf ^ 1][w * 512]);
      asm volatile("s_waitcnt vmcnt(2)" ::: "memory");
    } else {
      asm volatile("s_waitcnt vmcnt(0)" ::: "memory");
    }
    blockbar();

    const int kmin = j * 64;
    if (kmin <= row_max) {
      f32x4 s[4] = {};
      __builtin_amdgcn_s_setprio(1);
#pragma unroll
      for (int nb = 0; nb < 4; ++nb)
#pragma unroll
        for (int kk = 0; kk < 2; ++kk) {
          bf16x8 bk = *(const bf16x8*)&Ks[buf][(nb * 16 + llo) * 64 +
                                              ((kk * 32 + lhi * 8) ^ ((llo & 7) << 3))];
          s[nb] = __builtin_amdgcn_mfma_f32_16x16x32_bf16(aq[kk], bk, s[nb], 0, 0, 0);
        }
      __builtin_amdgcn_s_setprio(0);

      const bool part = (kmin + 63 > row_min);
      float sc[4][4];
#pragma unroll
      for (int nb = 0; nb < 4; ++nb)
#pragma unroll
        for (int i = 0; i < 4; ++i) {
          float v = s[nb][i];
          if (part && (kmin + llo * 4 + nb > row_min + lhi * 4 + i)) v = -1e30f;
          sc[nb][i] = v;
        }

      float rm[4];
#pragma unroll
      for (int i = 0; i < 4; ++i) {
        float r = fmaxf(fmaxf(sc[0][i], sc[1][i]), fmaxf(sc[2][i], sc[3][i]));
#pragma unroll
        for (int off = 1; off < 16; off <<= 1) r = fmaxf(r, __shfl_xor(r, off));
        rm[i] = r;
      }

      bool need = (rm[0] > m_i[0] + 8.f) | (rm[1] > m_i[1] + 8.f) |
                  (rm[2] > m_i[2] + 8.f) | (rm[3] > m_i[3] + 8.f);
      if (__any(need)) {
#pragma unroll
        for (int i = 0; i < 4; ++i) {
          float mn = fmaxf(m_i[i], rm[i]);
          float corr = exp2f(m_i[i] - mn);
          l_i[i] *= corr;
#pragma unroll
          for (int db = 0; db < 4; ++db) o[db][i] *= corr;
          m_i[i] = mn;
        }
      }

#pragma unroll
      for (int i = 0; i < 4; ++i) {
        float p0 = exp2f(sc[0][i] - m_i[i]);
        float p1 = exp2f(sc[1][i] - m_i[i]);
        float p2 = exp2f(sc[2][i] - m_i[i]);
        float p3 = exp2f(sc[3][i] - m_i[i]);
        float rsum = (p0 + p1) + (p2 + p3);
#pragma unroll
        for (int off = 1; off < 16; off <<= 1) rsum += __shfl_xor(rsum, off);
        l_i[i] += rsum;
        u32x2 pk;
        pk[0] = (unsigned)f2bf(p0) | ((unsigned)f2bf(p1) << 16);
        pk[1] = (unsigned)f2bf(p2) | ((unsigned)f2bf(p3) << 16);
        *(u32x2*)&Ps[(w * 16 + lhi * 4 + i) * 72 + llo * 4] = pk;
      }

      bf16x8 pa[2];
#pragma unroll
      for (int kk = 0; kk < 2; ++kk)
        pa[kk] = *(const bf16x8*)&Ps[(w * 16 + llo) * 72 + kk * 32 + lhi * 8];
      __builtin_amdgcn_s_setprio(1);
#pragma unroll
      for (int db = 0; db < 4; ++db)
#pragma unroll
        for (int kk = 0; kk < 2; ++kk) {
          bf16x8 bv = *(const bf16x8*)&Vs[buf][(db * 16 + llo) * 64 +
                                              ((kk * 32 + lhi * 8) ^ ((llo & 7) << 3))];
          o[db] = __builtin_amdgcn_mfma_f32_16x16x32_bf16(pa[kk], bv, o[db], 0, 0, 0);
        }
      __builtin_amdgcn_s_setprio(0);
    }
    blockbar();
    buf ^= 1;
  }

#pragma unroll
  for (int i = 0; i < 4; ++i) {
    float inv = 1.f / l_i[i];
    size_t row = tok0 + q0 + w * 16 + lhi * 4 + i;
#pragma unroll
    for (int db = 0; db < 4; ++db)
      y[row * CC_ + h * 64 + db * 16 + llo] = f2bf(o[db][i] * inv);
  }
}

extern "C" void kernel_launch(void* const* d_in, const int* in_sizes, int n_in,
                              void* d_out, int out_size, void* d_ws, size_t ws_size,
                              hipStream_t stream) {
  (void)in_sizes; (void)n_in; (void)out_size; (void)ws_size;
  const float* x      = (const float*)d_in[0];
  const float* ln1g   = (const float*)d_in[1];
  const float* ln1b   = (const float*)d_in[2];
  const float* W_attn = (const float*)d_in[3];
  const float* b_attn = (const float*)d_in[4];
  const float* W_ap   = (const float*)d_in[5];
  const float* b_ap   = (const float*)d_in[6];
  const float* ln2g   = (const float*)d_in[7];
  const float* ln2b   = (const float*)d_in[8];
  const float* W_fc   = (const float*)d_in[9];
  const float* b_fc   = (const float*)d_in[10];
  const float* W_mp   = (const float*)d_in[11];
  const float* b_mp   = (const float*)d_in[12];

  // ws layout: WTmp FIRST (live during mp); WTattn/WTap/WTfc+xn form a contiguous
  // dead region at mp time used for the 3 bf16 split-K partials (24MB needed).
  char* p = (char*)d_ws;
  u16* WTmp   = (u16*)p; p += (size_t)4096 * 1024 * 2;   // 8MB
  u16* WTattn = (u16*)p; p += (size_t)3072 * 1024 * 2;   // 6MB
  u16* WTap   = (u16*)p; p += (size_t)1024 * 1024 * 2;   // 2MB
  u16* WTfc   = (u16*)p; p += (size_t)4096 * 1024 * 2;   // 8MB
  u16* xn     = (u16*)p; p += (size_t)4096 * 1024 * 2;   // 8MB
  u16* qkvb   = (u16*)p; p += (size_t)4096 * 3072 * 2;
  u16* yb     = (u16*)p; p += (size_t)4096 * 1024 * 2;
  float* x1   = (float*)p; p += (size_t)4096 * 1024 * 4;
  u16* h2     = (u16*)p; p += (size_t)4096 * 1024 * 2;
  u16* fcb    = qkvb;           // fc activations alias qkv+yb (dead by then)
  u16* VT     = (u16*)x1;       // VT aliases x1 (x1 written after attn)
  u16* mpp    = WTattn;         // 3 bf16 partials (24MB over WTattn+WTap+WTfc)

  kconv_t<<<dim3(96, 32), 256, 0, stream>>>(W_attn, WTattn, 1024, 3072);
  kconv_t<<<dim3(32, 32), 256, 0, stream>>>(W_ap, WTap, 1024, 1024);
  kconv_t<<<dim3(128, 32), 256, 0, stream>>>(W_fc, WTfc, 1024, 4096);
  kconv_t<<<dim3(32, 128), 256, 0, stream>>>(W_mp, WTmp, 4096, 1024);

  kln<<<4096, 256, 0, stream>>>(x, ln1g, ln1b, xn);
  kgemm2<0, 1><<<dim3(12, 16), 512, 0, stream>>>(xn, WTattn, b_attn, nullptr, qkvb, nullptr, 4096, 3072, 1024);
  kvtrans<<<dim3(32, 32), 256, 0, stream>>>(qkvb, VT);
  kattn<<<dim3(16, 2, 16), 512, 0, stream>>>(qkvb, VT, yb);
  kgemm<1, 1><<<dim3(8, 32), 256, 0, stream>>>(yb, WTap, b_ap, x, x1, nullptr, 4096, 1024, 1024);
  kln<<<4096, 256, 0, stream>>>(x1, ln2g, ln2b, h2);
  kgemm2<2, 1><<<dim3(16, 16), 512, 0, stream>>>(h2, WTfc, b_fc, nullptr, fcb, nullptr, 4096, 4096, 1024);
  kgemm2<1, 4><<<dim3(4, 16, 4), 512, 0, stream>>>(fcb, WTmp, b_mp, x1, (float*)d_out, mpp, 4096, 1024, 4096);
  kadd3<<<2048, 256, 0, stream>>>((float*)d_out, mpp, (size_t)4096 * 1024);
}

// Round 6
// 273.839 us; speedup vs baseline: 1.0336x; 1.0336x over previous
//
#include <hip/hip_runtime.h>
#include <stdint.h>

#define TT_ 2048
#define CC_ 1024

typedef unsigned short u16;
typedef __bf16 bf16x8 __attribute__((ext_vector_type(8)));
typedef __bf16 bf16x4 __attribute__((ext_vector_type(4)));
typedef float f32x4 __attribute__((ext_vector_type(4)));
typedef unsigned short u16x8 __attribute__((ext_vector_type(8)));

__device__ __forceinline__ u16 f2bf(float f) {
  unsigned u = __float_as_uint(f);
  u += 0x7fff + ((u >> 16) & 1);
  return (u16)(u >> 16);
}
__device__ __forceinline__ float bf2f(u16 v) {
  return __uint_as_float(((unsigned)v) << 16);
}

__device__ __forceinline__ float gelu_f(float t) {
  float u = 1.5957691216057308f * (t + 0.044715f * t * t * t);
  return t / (1.f + __expf(-u));
}

__device__ __forceinline__ void async_cp16(const u16* g, u16* l) {
  __builtin_amdgcn_global_load_lds(
      (const __attribute__((address_space(1))) void*)(uintptr_t)g,
      (__attribute__((address_space(3))) void*)(uint32_t)(uintptr_t)l,
      16, 0, 0);
}

__device__ __forceinline__ void blockbar() {
  asm volatile("" ::: "memory");
  __builtin_amdgcn_s_barrier();
  asm volatile("" ::: "memory");
}

// ---- transpose + convert: W[K][N] f32 -> WT[N][K] bf16 ----
__global__ __launch_bounds__(256) void kconv_t(const float* __restrict__ W,
                                               u16* __restrict__ WT, int K, int N) {
  __shared__ float t[32][33];
  int n0 = blockIdx.x * 32, k0 = blockIdx.y * 32;
  int tx = threadIdx.x & 31, ty = threadIdx.x >> 5;
#pragma unroll
  for (int r = 0; r < 4; ++r)
    t[ty + 8 * r][tx] = W[(size_t)(k0 + ty + 8 * r) * N + n0 + tx];
  __syncthreads();
#pragma unroll
  for (int r = 0; r < 4; ++r)
    WT[(size_t)(n0 + ty + 8 * r) * K + k0 + tx] = f2bf(t[tx][ty + 8 * r]);
}

// ---- layernorm rows of 1024: f32 in -> bf16 out ----
__global__ __launch_bounds__(256) void kln(const float* __restrict__ x,
                                           const float* __restrict__ g,
                                           const float* __restrict__ b,
                                           u16* __restrict__ out) {
  int row = blockIdx.x, tid = threadIdx.x;
  const float4* xr = (const float4*)(x + (size_t)row * CC_);
  float4 v = xr[tid];
  float s = v.x + v.y + v.z + v.w;
  float s2 = v.x * v.x + v.y * v.y + v.z * v.z + v.w * v.w;
#pragma unroll
  for (int off = 32; off; off >>= 1) { s += __shfl_down(s, off); s2 += __shfl_down(s2, off); }
  __shared__ float rs[4], rq[4];
  int w = tid >> 6;
  if ((tid & 63) == 0) { rs[w] = s; rq[w] = s2; }
  __syncthreads();
  s = rs[0] + rs[1] + rs[2] + rs[3];
  s2 = rq[0] + rq[1] + rq[2] + rq[3];
  float mean = s * (1.f / CC_);
  float var = s2 * (1.f / CC_) - mean * mean;
  float rstd = rsqrtf(var + 1e-5f);
  float4 gv = ((const float4*)g)[tid];
  float4 bv = ((const float4*)b)[tid];
  u16* orow = out + (size_t)row * CC_ + tid * 4;
  orow[0] = f2bf((v.x - mean) * rstd * gv.x + bv.x);
  orow[1] = f2bf((v.y - mean) * rstd * gv.y + bv.y);
  orow[2] = f2bf((v.z - mean) * rstd * gv.z + bv.z);
  orow[3] = f2bf((v.w - mean) * rstd * gv.w + bv.w);
}

// ---- 128x128 GEMM, dbuf single-barrier K-loop (proven) ----
template <int EPI, int NSPLIT>
__global__ __launch_bounds__(256) void kgemm(const u16* __restrict__ A,
                                             const u16* __restrict__ BTm,
                                             const float* __restrict__ bias,
                                             const float* __restrict__ resid,
                                             void* __restrict__ out,
                                             float* __restrict__ part,
                                             int M, int N, int Ktot) {
  __shared__ __align__(16) u16 As[2][128 * 32];
  __shared__ __align__(16) u16 Bs[2][128 * 32];
  const int tid = threadIdx.x, lane = tid & 63, w = tid >> 6;
  const int llo = lane & 15, lhi = lane >> 4;
  const int row0 = blockIdx.y * 128, col0 = blockIdx.x * 128;
  const int wr = w >> 1, wc = w & 1;
  const int crow = lane >> 2;
  const int ck = (lane & 3) * 8;
  const int Kc = Ktot / NSPLIT;
  const int klo = (NSPLIT > 1) ? blockIdx.z * Kc : 0;

  f32x4 acc[4][4] = {};

  auto stage = [&](int bufi, int kof) {
#pragma unroll
    for (int c = w; c < 8; c += 4) {
      int r = c * 16 + crow;
      async_cp16(A + (size_t)(row0 + r) * Ktot + klo + kof + ck, &As[bufi][c * 512]);
      async_cp16(BTm + (size_t)(col0 + r) * Ktot + klo + kof + ck, &Bs[bufi][c * 512]);
    }
  };

  const int nt = Kc / 32;
  stage(0, 0);
  asm volatile("s_waitcnt vmcnt(0)" ::: "memory");
  blockbar();
  int cur = 0;

  for (int t = 0; t < nt; ++t) {
    if (t + 1 < nt) stage(cur ^ 1, (t + 1) * 32);
    bf16x8 af[4], bfr[4];
#pragma unroll
    for (int m = 0; m < 4; ++m)
      af[m] = *(const bf16x8*)&As[cur][(wr * 64 + m * 16 + llo) * 32 + lhi * 8];
#pragma unroll
    for (int n = 0; n < 4; ++n)
      bfr[n] = *(const bf16x8*)&Bs[cur][(wc * 64 + n * 16 + llo) * 32 + lhi * 8];
#pragma unroll
    for (int m = 0; m < 4; ++m)
#pragma unroll
      for (int n = 0; n < 4; ++n)
        acc[m][n] = __builtin_amdgcn_mfma_f32_16x16x32_bf16(af[m], bfr[n], acc[m][n], 0, 0, 0);
    if (t + 1 < nt) {
      asm volatile("s_waitcnt vmcnt(0)" ::: "memory");
      blockbar();
    }
    cur ^= 1;
  }

  const int c_row = row0 + wr * 64 + lhi * 4;
  const int c_col = col0 + wc * 64 + llo;
  const bool fin = (NSPLIT == 1) || (blockIdx.z == 0);
#pragma unroll
  for (int n = 0; n < 4; ++n) {
    int col = c_col + n * 16;
    float bb = bias[col];
#pragma unroll
    for (int m = 0; m < 4; ++m) {
      f32x4 a = acc[m][n];
#pragma unroll
      for (int i = 0; i < 4; ++i) {
        size_t idx = (size_t)(c_row + m * 16 + i) * N + col;
        if (!fin) {
          part[idx] = a[i];
        } else {
          float val = a[i] + bb;
          if constexpr (EPI == 1) {
            ((float*)out)[idx] = val + resid[idx];
          } else if constexpr (EPI == 2) {
            ((u16*)out)[idx] = f2bf(gelu_f(val));
          } else {
            ((u16*)out)[idx] = f2bf(val);
          }
        }
      }
    }
  }
}

// ---- 256x256 GEMM, BK=32, 4-slot LDS ring, distance-3 prefetch, counted vmcnt ----
template <int EPI, int NSPLIT>
__global__ __launch_bounds__(512, 2) void kgemm2(const u16* __restrict__ A,
                                                 const u16* __restrict__ BTm,
                                                 const float* __restrict__ bias,
                                                 const float* __restrict__ resid,
                                                 void* __restrict__ out,
                                                 u16* __restrict__ part,
                                                 int M, int N, int Ktot) {
  __shared__ __align__(16) u16 LB[4][2][8192];
  const int tid = threadIdx.x, lane = tid & 63, w = tid >> 6;
  const int llo = lane & 15, lhi = lane >> 4;
  const int wr = w >> 2, wc = w & 3;
  const int row0 = blockIdx.y * 256, col0 = blockIdx.x * 256;
  const int Kc = Ktot / NSPLIT;
  const int klo = (NSPLIT > 1) ? blockIdx.z * Kc : 0;
  const int nt = Kc / 32;

  const int wsA = w & 3;
  const int hbB = (wc >> 1);
  const int wsB = (w & 1) + ((w >> 2) << 1);

  const u16 *gA[2], *gB[2];
  int ldsA[2], ldsB[2];
#pragma unroll
  for (int l = 0; l < 2; ++l) {
    int c = l * 256 + wsA * 64 + lane;
    int rowl = c >> 2;
    int kc = ((c & 3) ^ ((c >> 3) & 3)) * 8;
    gA[l] = A + (size_t)(row0 + wr * 128 + rowl) * Ktot + klo + kc;
    ldsA[l] = wr * 4096 + (l * 256 + wsA * 64) * 8;
    int c2 = l * 256 + wsB * 64 + lane;
    int row2 = c2 >> 2;
    int kc2 = ((c2 & 3) ^ ((c2 >> 3) & 3)) * 8;
    gB[l] = BTm + (size_t)(col0 + hbB * 128 + row2) * Ktot + klo + kc2;
    ldsB[l] = hbB * 4096 + (l * 256 + wsB * 64) * 8;
  }

  auto stage = [&](int t) {
    int slot = t & 3;
#pragma unroll
    for (int l = 0; l < 2; ++l) {
      async_cp16(gA[l] + (size_t)t * 32, &LB[slot][0][ldsA[l]]);
      async_cp16(gB[l] + (size_t)t * 32, &LB[slot][1][ldsB[l]]);
    }
  };

  f32x4 acc[8][4] = {};
  for (int t = 0; t < 3 && t < nt; ++t) stage(t);
  const int swz = (llo >> 1) & 3;
  const int aoffb = wr * 4096 + llo * 32 + (lhi ^ swz) * 8;
  const int boffb = hbB * 4096 + ((wc & 1) * 64 + llo) * 32 + (lhi ^ swz) * 8;

  for (int t = 0; t < nt; ++t) {
    const int slot = t & 3;
    const int rem = nt - 1 - t;
    if (rem >= 2)      asm volatile("s_waitcnt vmcnt(8)" ::: "memory");
    else if (rem == 1) asm volatile("s_waitcnt vmcnt(4)" ::: "memory");
    else               asm volatile("s_waitcnt vmcnt(0)" ::: "memory");
    asm volatile("s_waitcnt lgkmcnt(0)" ::: "memory");
    blockbar();
    if (t + 3 < nt) stage(t + 3);

    bf16x8 af[8], bfv[4];
#pragma unroll
    for (int n = 0; n < 4; ++n)
      bfv[n] = *(const bf16x8*)&LB[slot][1][boffb + n * 512];
#pragma unroll
    for (int m = 0; m < 8; ++m)
      af[m] = *(const bf16x8*)&LB[slot][0][aoffb + m * 512];
    __builtin_amdgcn_s_setprio(1);
#pragma unroll
    for (int m = 0; m < 8; ++m)
#pragma unroll
      for (int n = 0; n < 4; ++n)
        acc[m][n] = __builtin_amdgcn_mfma_f32_16x16x32_bf16(af[m], bfv[n], acc[m][n], 0, 0, 0);
    __builtin_amdgcn_s_setprio(0);
  }

  const int c_row0 = row0 + wr * 128 + lhi * 4;
  const int c_col0 = col0 + wc * 64 + llo;
  const bool fin = (NSPLIT == 1) || (blockIdx.z == 0);
  u16* pb = part + (NSPLIT > 1 ? ((size_t)(blockIdx.z - 1)) * M * N : 0);
#pragma unroll
  for (int n = 0; n < 4; ++n) {
    int col = c_col0 + n * 16;
    float bb = bias[col];
#pragma unroll
    for (int m = 0; m < 8; ++m) {
      f32x4 a = acc[m][n];
#pragma unroll
      for (int i = 0; i < 4; ++i) {
        size_t idx = (size_t)(c_row0 + m * 16 + i) * N + col;
        if (!fin) {
          pb[idx] = f2bf(a[i]);
        } else {
          float val = a[i] + bb;
          if constexpr (EPI == 1) {
            ((float*)out)[idx] = val + resid[idx];
          } else if constexpr (EPI == 2) {
            ((u16*)out)[idx] = f2bf(gelu_f(val));
          } else {
            ((u16*)out)[idx] = f2bf(val);
          }
        }
      }
    }
  }
}

// ---- out[i] += p1[i]+p2[i]+p3[i] (bf16 partials) ----
__global__ __launch_bounds__(256) void kadd3(float* __restrict__ out,
                                             const u16* __restrict__ p, size_t MN) {
  size_t i0 = ((size_t)blockIdx.x * 256 + threadIdx.x) * 8;
  float4 o0 = *(float4*)(out + i0);
  float4 o1 = *(float4*)(out + i0 + 4);
#pragma unroll
  for (int s = 0; s < 3; ++s) {
    u16x8 v = *(const u16x8*)(p + s * MN + i0);
    o0.x += bf2f(v[0]); o0.y += bf2f(v[1]); o0.z += bf2f(v[2]); o0.w += bf2f(v[3]);
    o1.x += bf2f(v[4]); o1.y += bf2f(v[5]); o1.z += bf2f(v[6]); o1.w += bf2f(v[7]);
  }
  *(float4*)(out + i0) = o0;
  *(float4*)(out + i0 + 4) = o1;
}

// ---- V transpose: qkv[.][2048+h*64+d] -> VT[bh][d][T] bf16 ----
__global__ __launch_bounds__(256) void kvtrans(const u16* __restrict__ qkv,
                                               u16* __restrict__ VT) {
  int tt = blockIdx.x;
  int bh = blockIdx.y;
  int b = bh >> 4, h = bh & 15;
  __shared__ u16 t[64][72];
  int r = threadIdx.x >> 3, c0 = (threadIdx.x & 7) * 8;
  const u16* src = qkv + (size_t)(b * TT_ + tt * 64) * 3072 + 2048 + h * 64;
#pragma unroll
  for (int it = 0; it < 2; ++it) {
    int rr = r + it * 32;
    *(u16x8*)&t[rr][c0] = *(const u16x8*)(src + (size_t)rr * 3072 + c0);
  }
  __syncthreads();
  u16* dst = VT + ((size_t)bh * 64) * TT_ + tt * 64;
#pragma unroll
  for (int it = 0; it < 2; ++it) {
    int d = r + it * 32;
    u16x8 v;
#pragma unroll
    for (int e = 0; e < 8; ++e) v[e] = t[c0 + e][d];
    *(u16x8*)(dst + (size_t)d * TT_ + c0) = v;
  }
}

// ---- causal flash attention: 4 waves, QBLK=64, two q-supertiles per block
//      (z and 31-z -> every block does exactly 33 k-tiles), dbuf K/V,
//      K-row-permuted LDS, exp2 softmax w/ defer-max, per-lane l ----
__global__ __launch_bounds__(256, 4) void kattn(const u16* __restrict__ qkv,
                                                const u16* __restrict__ VT,
                                                u16* __restrict__ y) {
  const int h = blockIdx.x, b = blockIdx.y, z = blockIdx.z;  // z 0..15
  const int tid = threadIdx.x, lane = tid & 63, w = tid >> 6;  // w 0..3
  const int llo = lane & 15, lhi = lane >> 4;

  __shared__ __align__(16) u16 Qs[64 * 64];
  __shared__ __align__(16) u16 Ks[2][64 * 64];
  __shared__ __align__(16) u16 Vs[2][64 * 64];
  __shared__ __align__(16) u16 Ps[64 * 72];

  const size_t tok0 = (size_t)b * TT_;
  const u16* qb = qkv + tok0 * 3072 + h * 64;
  const u16* kb = qb + 1024;

  // per-lane K/V staging addresses (2 row-groups of 8 per wave)
  const u16 *kg[2], *vg[2];
#pragma unroll
  for (int it = 0; it < 2; ++it) {
    int p_ = w * 16 + it * 8 + (lane >> 3);          // LDS row 0..63
    int krow = ((p_ & 15) << 2) | (p_ >> 4);         // K-row permutation (inverse)
    int scol = ((lane & 7) * 8) ^ ((p_ & 7) << 3);   // pre-swizzled source col
    kg[it] = kb + (size_t)krow * 3072 + scol;
    vg[it] = VT + ((size_t)(b * 16 + h) * 64 + p_) * TT_ + scol;
  }

  auto stageKV = [&](int bufi, int j) {
    async_cp16(kg[0] + (size_t)j * (64 * 3072), &Ks[bufi][(w * 16 + 0) * 64]);
    async_cp16(kg[1] + (size_t)j * (64 * 3072), &Ks[bufi][(w * 16 + 8) * 64]);
    async_cp16(vg[0] + (size_t)j * 64, &Vs[bufi][(w * 16 + 0) * 64]);
    async_cp16(vg[1] + (size_t)j * 64, &Vs[bufi][(w * 16 + 8) * 64]);
  };

  const float alpha = 0.18033688011112042f;  // 0.125 * log2(e)
  const int r8 = tid >> 3, ce = (tid & 7) * 8;

#pragma unroll 1
  for (int ph = 0; ph < 2; ++ph) {
    const int qt = ph ? (31 - z) : z;
    const int q0 = qt * 64;

    // stage Q (scaled into exp2 domain), swizzled rows
#pragma unroll
    for (int it = 0; it < 2; ++it) {
      int tk = it * 32 + r8;
      u16x8 v = *(const u16x8*)(qb + (size_t)(q0 + tk) * 3072 + ce);
#pragma unroll
      for (int e = 0; e < 8; ++e) v[e] = f2bf(bf2f(v[e]) * alpha);
      *(u16x8*)&Qs[tk * 64 + (ce ^ ((tk & 7) << 3))] = v;
    }
    asm volatile("s_waitcnt lgkmcnt(0)" ::: "memory");
    stageKV(0, 0);
    blockbar();  // Q visible to all waves

    bf16x8 aq[2];
#pragma unroll
    for (int kk = 0; kk < 2; ++kk)
      aq[kk] = *(const bf16x8*)&Qs[(w * 16 + llo) * 64 +
                                   ((kk * 32 + lhi * 8) ^ ((llo & 7) << 3))];

    float m_i[4], l_i[4];
    f32x4 o[4] = {};
#pragma unroll
    for (int i = 0; i < 4; ++i) { m_i[i] = -1e30f; l_i[i] = 0.f; }

    int buf = 0;
    for (int j = 0; j <= qt; ++j) {
      if (j < qt) {
        stageKV(buf ^ 1, j + 1);
        asm volatile("s_waitcnt vmcnt(4)" ::: "memory");
      } else {
        asm volatile("s_waitcnt vmcnt(0)" ::: "memory");
      }
      blockbar();

      // S' = (alpha*Q) K^T
      f32x4 s[4] = {};
      __builtin_amdgcn_s_setprio(1);
#pragma unroll
      for (int nb = 0; nb < 4; ++nb)
#pragma unroll
        for (int kk = 0; kk < 2; ++kk) {
          bf16x8 bk = *(const bf16x8*)&Ks[buf][(nb * 16 + llo) * 64 +
                                              ((kk * 32 + lhi * 8) ^ ((llo & 7) << 3))];
          s[nb] = __builtin_amdgcn_mfma_f32_16x16x32_bf16(aq[kk], bk, s[nb], 0, 0, 0);
        }
      __builtin_amdgcn_s_setprio(0);

      // mask only on the diagonal tile (wave-uniform branch)
      float sc[4][4];
      if (j == qt) {
#pragma unroll
        for (int nb = 0; nb < 4; ++nb)
#pragma unroll
          for (int i = 0; i < 4; ++i) {
            float v = s[nb][i];
            if (llo * 4 + nb > w * 16 + lhi * 4 + i) v = -1e30f;
            sc[nb][i] = v;
          }
      } else {
#pragma unroll
        for (int nb = 0; nb < 4; ++nb)
#pragma unroll
          for (int i = 0; i < 4; ++i) sc[nb][i] = s[nb][i];
      }

      // row maxes (16-lane groups)
      float rm[4];
#pragma unroll
      for (int i = 0; i < 4; ++i) {
        float r = fmaxf(fmaxf(sc[0][i], sc[1][i]), fmaxf(sc[2][i], sc[3][i]));
#pragma unroll
        for (int off = 1; off < 16; off <<= 1) r = fmaxf(r, __shfl_xor(r, off));
        rm[i] = r;
      }

      bool need = (rm[0] > m_i[0] + 8.f) | (rm[1] > m_i[1] + 8.f) |
                  (rm[2] > m_i[2] + 8.f) | (rm[3] > m_i[3] + 8.f);
      if (__any(need)) {
#pragma unroll
        for (int i = 0; i < 4; ++i) {
          float mn = fmaxf(m_i[i], rm[i]);
          float corr = exp2f(m_i[i] - mn);
          l_i[i] *= corr;
#pragma unroll
          for (int db = 0; db < 4; ++db) o[db][i] *= corr;
          m_i[i] = mn;
        }
      }

#pragma unroll
      for (int i = 0; i < 4; ++i) {
        float p0 = exp2f(sc[0][i] - m_i[i]);
        float p1 = exp2f(sc[1][i] - m_i[i]);
        float p2 = exp2f(sc[2][i] - m_i[i]);
        float p3 = exp2f(sc[3][i] - m_i[i]);
        l_i[i] += (p0 + p1) + (p2 + p3);   // per-lane partial; reduce once at end
        bf16x4 pk = {(__bf16)p0, (__bf16)p1, (__bf16)p2, (__bf16)p3};
        *(bf16x4*)&Ps[(w * 16 + lhi * 4 + i) * 72 + llo * 4] = pk;
      }

      // O += P V
      bf16x8 pa[2];
#pragma unroll
      for (int kk = 0; kk < 2; ++kk)
        pa[kk] = *(const bf16x8*)&Ps[(w * 16 + llo) * 72 + kk * 32 + lhi * 8];
      __builtin_amdgcn_s_setprio(1);
#pragma unroll
      for (int db = 0; db < 4; ++db)
#pragma unroll
        for (int kk = 0; kk < 2; ++kk) {
          bf16x8 bv = *(const bf16x8*)&Vs[buf][(db * 16 + llo) * 64 +
                                              ((kk * 32 + lhi * 8) ^ ((llo & 7) << 3))];
          o[db] = __builtin_amdgcn_mfma_f32_16x16x32_bf16(pa[kk], bv, o[db], 0, 0, 0);
        }
      __builtin_amdgcn_s_setprio(0);
      blockbar();
      buf ^= 1;
    }

    // final l reduce across the 16-lane row group, then write O
#pragma unroll
    for (int i = 0; i < 4; ++i) {
      float t = l_i[i];
#pragma unroll
      for (int off = 1; off < 16; off <<= 1) t += __shfl_xor(t, off);
      float inv = 1.f / t;
      size_t row = tok0 + q0 + w * 16 + lhi * 4 + i;
#pragma unroll
      for (int db = 0; db < 4; ++db)
        y[row * CC_ + h * 64 + db * 16 + llo] = f2bf(o[db][i] * inv);
    }
  }
}

extern "C" void kernel_launch(void* const* d_in, const int* in_sizes, int n_in,
                              void* d_out, int out_size, void* d_ws, size_t ws_size,
                              hipStream_t stream) {
  (void)in_sizes; (void)n_in; (void)out_size; (void)ws_size;
  const float* x      = (const float*)d_in[0];
  const float* ln1g   = (const float*)d_in[1];
  const float* ln1b   = (const float*)d_in[2];
  const float* W_attn = (const float*)d_in[3];
  const float* b_attn = (const float*)d_in[4];
  const float* W_ap   = (const float*)d_in[5];
  const float* b_ap   = (const float*)d_in[6];
  const float* ln2g   = (const float*)d_in[7];
  const float* ln2b   = (const float*)d_in[8];
  const float* W_fc   = (const float*)d_in[9];
  const float* b_fc   = (const float*)d_in[10];
  const float* W_mp   = (const float*)d_in[11];
  const float* b_mp   = (const float*)d_in[12];

  char* p = (char*)d_ws;
  u16* WTmp   = (u16*)p; p += (size_t)4096 * 1024 * 2;   // live during mp
  u16* WTattn = (u16*)p; p += (size_t)3072 * 1024 * 2;
  u16* WTap   = (u16*)p; p += (size_t)1024 * 1024 * 2;
  u16* WTfc   = (u16*)p; p += (size_t)4096 * 1024 * 2;
  u16* xn     = (u16*)p; p += (size_t)4096 * 1024 * 2;
  u16* qkvb   = (u16*)p; p += (size_t)4096 * 3072 * 2;
  u16* yb     = (u16*)p; p += (size_t)4096 * 1024 * 2;
  float* x1   = (float*)p; p += (size_t)4096 * 1024 * 4;
  u16* h2     = (u16*)p; p += (size_t)4096 * 1024 * 2;
  u16* fcb    = qkvb;           // fc activations alias qkv+yb (dead by then)
  u16* VT     = (u16*)x1;       // VT aliases x1 (x1 written after attn)
  u16* mpp    = WTattn;         // 3 bf16 partials (24MB over WTattn+WTap+WTfc)

  kconv_t<<<dim3(96, 32), 256, 0, stream>>>(W_attn, WTattn, 1024, 3072);
  kconv_t<<<dim3(32, 32), 256, 0, stream>>>(W_ap, WTap, 1024, 1024);
  kconv_t<<<dim3(128, 32), 256, 0, stream>>>(W_fc, WTfc, 1024, 4096);
  kconv_t<<<dim3(32, 128), 256, 0, stream>>>(W_mp, WTmp, 4096, 1024);

  kln<<<4096, 256, 0, stream>>>(x, ln1g, ln1b, xn);
  kgemm<0, 1><<<dim3(24, 32), 256, 0, stream>>>(xn, WTattn, b_attn, nullptr, qkvb, nullptr, 4096, 3072, 1024);
  kvtrans<<<dim3(32, 32), 256, 0, stream>>>(qkvb, VT);
  kattn<<<dim3(16, 2, 16), 256, 0, stream>>>(qkvb, VT, yb);
  kgemm<1, 1><<<dim3(8, 32), 256, 0, stream>>>(yb, WTap, b_ap, x, x1, nullptr, 4096, 1024, 1024);
  kln<<<4096, 256, 0, stream>>>(x1, ln2g, ln2b, h2);
  kgemm2<2, 1><<<dim3(16, 16), 512, 0, stream>>>(h2, WTfc, b_fc, nullptr, fcb, nullptr, 4096, 4096, 1024);
  kgemm2<1, 4><<<dim3(4, 16, 4), 512, 0, stream>>>(fcb, WTmp, b_mp, x1, (float*)d_out, mpp, 4096, 1024, 4096);
  kadd3<<<2048, 256, 0, stream>>>((float*)d_out, mpp, (size_t)4096 * 1024);
}